// Round 7
// baseline (224.796 us; speedup 1.0000x reference)
//
#include <hip/hip_runtime.h>
#include <math.h>

// Problem constants
#define NN 8
#define C_TOTAL 448
#define CC 100
#define HH 56
#define WW 56
#define HW (HH*WW)          // 3136
#define NPIX4 (HW/4)        // 784 quads (float4 pixel groups)
#define OH 224
#define OW 224
#define NT4 13              // ceil(784/64) quad tiles
#define NG 25               // row groups of 4: group k = rows 4k..4k+3
#define CHB 8               // streamed chunk width (columns per LDS buffer)

typedef __attribute__((ext_vector_type(4))) _Float16 half4;
typedef __attribute__((ext_vector_type(8))) _Float16 half8;
typedef __attribute__((ext_vector_type(4))) float    f32x4;

__device__ __forceinline__ f32x4 cvtlo(const half8 h) {
    return __builtin_convertvector(__builtin_shufflevector(h, h, 0, 1, 2, 3), f32x4);
}
__device__ __forceinline__ f32x4 cvthi(const half8 h) {
    return __builtin_convertvector(__builtin_shufflevector(h, h, 4, 5, 6, 7), f32x4);
}
__device__ __forceinline__ f32x4 fmav(const f32x4 a, const f32x4 b, const f32x4 c) {
    f32x4 r;
    r.x = fmaf(a.x, b.x, c.x);
    r.y = fmaf(a.y, b.y, c.y);
    r.z = fmaf(a.z, b.z, c.z);
    r.w = fmaf(a.w, b.w, c.w);
    return r;
}

// async global->LDS DMA: 16 B per lane, LDS dest = wave-uniform base + lane*16
#define GL_LDS(gp, lp) \
  __builtin_amdgcn_global_load_lds((const __attribute__((address_space(1))) void*)(gp), \
                                   (__attribute__((address_space(3))) void*)(lp), 16, 0, 0)

// ---------------------------------------------------------------------------
// Kernel 0: x -> fp16, TRANSPOSED layout xbuf[c][quad][n] (half4 elements).
// Also zeroes the smap accumulator (first NN*NPIX4 threads).
// ---------------------------------------------------------------------------
__global__ __launch_bounds__(256) void prep_x_kernel(
    const float* __restrict__ fmaps, const int* __restrict__ sel,
    const float* __restrict__ mean, half4* __restrict__ xbuf,
    float* __restrict__ smap)
{
    const int idx = blockIdx.x * 256 + threadIdx.x;
    if (idx < NN * NPIX4) {
        ((float4*)smap)[idx] = make_float4(0.f, 0.f, 0.f, 0.f);
    }
    if (idx >= CC * NPIX4) return;
    const int quad = idx % NPIX4;
    const int c    = idx / NPIX4;

    const float4* f4 = (const float4*)fmaps;
    const float4  m  = ((const float4*)mean)[(size_t)c * NPIX4 + quad];
    const int     sc = sel[c];

    half4 hv[NN];
#pragma unroll
    for (int n = 0; n < NN; ++n) {
        const float4 f = f4[((size_t)n * C_TOTAL + sc) * NPIX4 + quad];
        half4 h;
        h.x = (_Float16)(f.x - m.x);
        h.y = (_Float16)(f.y - m.y);
        h.z = (_Float16)(f.z - m.z);
        h.w = (_Float16)(f.w - m.w);
        hv[n] = h;
    }
    half4* dst = xbuf + ((size_t)c * NPIX4 + quad) * NN;   // 64 B contiguous
#pragma unroll
    for (int n = 0; n < NN; ++n) dst[n] = hv[n];
}

// ---------------------------------------------------------------------------
// Kernel 1: ASYNC-STAGED qform. Diagnosis (R5/R6): qform invariant at ~43 µs
// across occupancy/grouping changes -> per-wave synchronous load->wait->FMA
// pattern, ~4100 cyc/iter of exposed HBM latency. Fix: global_load_lds
// double-buffered cov staging (issue decoupled from consumption, dedups the
// imgh-duplicate cov requests, no VGPR round-trip).
//   Block = (group k: rows a..a+3, a=4k) x (64-quad tile). 325 blocks,
//   64 KB LDS -> 2 blocks/CU, all resident.
//   8 waves = (cph: col parity) x (rh: row half) x (imgh: image half).
//   Per 8-col chunk: wave w stages col chunk+w, 4 rows = 4 x GL_LDS (1 KB
//   slices, LDS [buf][col][row][lane] linear -> conforms to DMA layout).
//   Peel (registers): intra-group triangle d in [a,a+4), diag x0.5,
//   overlapped with the first stage. Tail cols: clamped staging (finite
//   data) + weight-0 multiply -> branch-free, exact.
//   lred (32 KB) overlaid on cov buffers after a barrier.
//   Epilogue: fold 2*x_r.acc_r, cross-wave LDS sum, atomicAdd into smap.
// ---------------------------------------------------------------------------
__global__ __launch_bounds__(512, 4) void qform_kernel(
    const half4* __restrict__ xbuf, const float* __restrict__ cov,
    float* __restrict__ smap)
{
    __shared__ __align__(16) char ldsraw[2 * CHB * 4 * 64 * 16];   // 64 KB

    const int tile = blockIdx.x % NT4;
    const int k    = blockIdx.x / NT4;   // 0..24 (ascending -> long blocks first)
    const int a    = 4 * k;

    const int w    = threadIdx.x >> 6;   // wave id 0..7
    const int cph  = w & 1;              // col parity within chunk
    const int rh   = (w >> 1) & 1;       // row half: rows a+2rh, a+2rh+1
    const int imgh = w >> 2;             // image half (0: n=0..3, 1: n=4..7)
    const int lane = threadIdx.x & 63;
    const int qraw = tile * 64 + lane;
    const bool valid = qraw < NPIX4;
    const int quad = valid ? qraw : (NPIX4 - 1);   // clamp, no early return

    const int r0 = a + 2 * rh;
    const int r1 = r0 + 1;

    const half8* xb8 = (const half8*)xbuf;
    f32x4* covlds = (f32x4*)ldsraw;      // [2][CHB][4][64]

    const int S0  = a + 4;                         // streamed cols start
    const int nch = (CC - S0 + CHB - 1) / CHB;     // 0..12 chunks

    f32x4 acc[2][4];                     // [row in half][img]
#pragma unroll
    for (int i = 0; i < 2; ++i)
#pragma unroll
        for (int j = 0; j < 4; ++j) acc[i][j] = (f32x4){0.f, 0.f, 0.f, 0.f};

    // ---- issue stage of chunk 0 FIRST (latency hides under the peel) ----
    if (nch > 0) {
        const int d  = S0 + w;           // w < CHB
        const int dc = (d < CC) ? d : (CC - 1);
#pragma unroll
        for (int i = 0; i < 4; ++i) {
            const float* g = cov + ((size_t)(a + i) * CC + dc) * HW + (size_t)quad * 4;
            GL_LDS(g, (char*)&covlds[((0 * CHB + w) * 4 + i) * 64]);
        }
    }

    // ---- peel: intra-group triangle d in [a, a+4), register path ----
#pragma unroll
    for (int dd = 0; dd < 2; ++dd) {
        const int d = a + 2 * dd + cph;
        const half8* xp = xb8 + ((size_t)d * NPIX4 + quad) * 4 + imgh * 2;
        const half8 hA = xp[0];
        const half8 hB = xp[1];
        f32x4 xv[4];
        xv[0] = cvtlo(hA); xv[1] = cvthi(hA);
        xv[2] = cvtlo(hB); xv[3] = cvthi(hB);
#pragma unroll
        for (int i = 0; i < 2; ++i) {
            const int r = r0 + i;
            if (r <= d) {                // wave-uniform
                f32x4 cv = __builtin_nontemporal_load(
                    (const f32x4*)(cov + ((size_t)r * CC + d) * HW + (size_t)quad * 4));
                if (r == d) cv *= 0.5f;
#pragma unroll
                for (int j = 0; j < 4; ++j) acc[i][j] = fmav(xv[j], cv, acc[i][j]);
            }
        }
    }

    // ---- streamed main: double-buffered LDS chunks ----
    if (nch > 0) {
        asm volatile("s_waitcnt vmcnt(0)" ::: "memory");
        __syncthreads();                 // buffer 0 ready for all waves
        int buf = 0;
        for (int ch = 0; ch < nch; ++ch) {
            if (ch + 1 < nch) {          // stage next chunk into buf^1
                const int d  = S0 + (ch + 1) * CHB + w;
                const int dc = (d < CC) ? d : (CC - 1);
#pragma unroll
                for (int i = 0; i < 4; ++i) {
                    const float* g = cov + ((size_t)(a + i) * CC + dc) * HW + (size_t)quad * 4;
                    GL_LDS(g, (char*)&covlds[(((buf ^ 1) * CHB + w) * 4 + i) * 64]);
                }
            }
            // compute chunk ch from buf
            const int cb = S0 + ch * CHB;
#pragma unroll
            for (int ci = 0; ci < 4; ++ci) {
                const int cl = 2 * ci + cph;
                const int d  = cb + cl;
                const float wt = (d < CC) ? 1.f : 0.f;
                const int  dc  = (d < CC) ? d : (CC - 1);
                const half8* xp = xb8 + ((size_t)dc * NPIX4 + quad) * 4 + imgh * 2;
                const half8 hA = xp[0];
                const half8 hB = xp[1];
                f32x4 xv[4];
                xv[0] = cvtlo(hA); xv[1] = cvthi(hA);
                xv[2] = cvtlo(hB); xv[3] = cvthi(hB);
                f32x4 cv0 = covlds[((buf * CHB + cl) * 4 + 2 * rh + 0) * 64 + lane];
                f32x4 cv1 = covlds[((buf * CHB + cl) * 4 + 2 * rh + 1) * 64 + lane];
                cv0 *= wt;               // tail cols: staged data finite, weight 0 exact
                cv1 *= wt;
#pragma unroll
                for (int j = 0; j < 4; ++j) acc[0][j] = fmav(xv[j], cv0, acc[0][j]);
#pragma unroll
                for (int j = 0; j < 4; ++j) acc[1][j] = fmav(xv[j], cv1, acc[1][j]);
            }
            asm volatile("s_waitcnt vmcnt(0)" ::: "memory");
            __syncthreads();             // next buffer ready; current safe to overwrite
            buf ^= 1;
        }
    }

    // ---- fold: part[j] = 2*(x_r0[j]*acc0[j] + x_r1[j]*acc1[j]) ----
    __syncthreads();                     // before aliasing LDS as lred
    f32x4* lred = (f32x4*)ldsraw;        // [8 waves][4 img-slots][64 lanes] = 32 KB
    {
        const half8* x0p = xb8 + ((size_t)r0 * NPIX4 + quad) * 4 + imgh * 2;
        const half8* x1p = xb8 + ((size_t)r1 * NPIX4 + quad) * 4 + imgh * 2;
        const half8 xa0 = x0p[0], xb0 = x0p[1];
        const half8 xa1 = x1p[0], xb1 = x1p[1];
        f32x4 part[4];
        part[0] = cvtlo(xa0) * acc[0][0];
        part[1] = cvthi(xa0) * acc[0][1];
        part[2] = cvtlo(xb0) * acc[0][2];
        part[3] = cvthi(xb0) * acc[0][3];
        part[0] = fmav(cvtlo(xa1), acc[1][0], part[0]);
        part[1] = fmav(cvthi(xa1), acc[1][1], part[1]);
        part[2] = fmav(cvtlo(xb1), acc[1][2], part[2]);
        part[3] = fmav(cvthi(xb1), acc[1][3], part[3]);
#pragma unroll
        for (int j = 0; j < 4; ++j) {
            part[j] = part[j] + part[j];             // x2 (symmetry)
            lred[(w * 4 + j) * 64 + lane] = part[j];
        }
    }
    __syncthreads();

    // ---- final: wave w sums image w over its 4 (cph, rh) partials ----
    {
        const int im = w;                // 0..7
        const int sh = (im >> 2) * 4;    // base wave of the matching imgh
        const int sl = im & 3;           // slot within image half
        f32x4 s = (f32x4){0.f, 0.f, 0.f, 0.f};
#pragma unroll
        for (int sw = 0; sw < 4; ++sw) {
            s = s + lred[((sh + sw) * 4 + sl) * 64 + lane];
        }
        if (valid) {
            float* dst = smap + (size_t)im * HW + (size_t)qraw * 4;
            atomicAdd(dst + 0, s.x);
            atomicAdd(dst + 1, s.y);
            atomicAdd(dst + 2, s.z);
            atomicAdd(dst + 3, s.w);
        }
    }
}

// ---------------------------------------------------------------------------
// Kernel 2: sqrt + bilinear x4 upsample (half-pixel, edge clamp) + normalize
// ---------------------------------------------------------------------------
__global__ __launch_bounds__(256) void upsample_kernel(
    const float* __restrict__ smap,
    const float* __restrict__ minp, const float* __restrict__ maxp,
    float* __restrict__ out)
{
    const int idx = blockIdx.x * 256 + threadIdx.x;
    const int total = NN * OH * OW;
    if (idx >= total) return;

    const int ox = idx % OW;
    const int oy = (idx / OW) % OH;
    const int n  = idx / (OW * OH);

    const float fy = oy * 0.25f - 0.375f;
    const float fx = ox * 0.25f - 0.375f;

    int y0 = (int)floorf(fy);
    int x0 = (int)floorf(fx);
    const float wy = fy - (float)y0;
    const float wx = fx - (float)x0;
    int y1 = min(y0 + 1, HH - 1); y0 = max(y0, 0);
    int x1 = min(x0 + 1, WW - 1); x0 = max(x0, 0);

    const float* s = smap + (size_t)n * HW;
    const float v00 = sqrtf(fmaxf(s[y0 * WW + x0], 0.f));
    const float v01 = sqrtf(fmaxf(s[y0 * WW + x1], 0.f));
    const float v10 = sqrtf(fmaxf(s[y1 * WW + x0], 0.f));
    const float v11 = sqrtf(fmaxf(s[y1 * WW + x1], 0.f));

    const float v = (1.0f - wy) * ((1.0f - wx) * v00 + wx * v01)
                  +          wy * ((1.0f - wx) * v10 + wx * v11);

    const float mn = *minp;
    const float mx = *maxp;
    out[idx] = (v - mn) / (mx - mn);
}

// ---------------------------------------------------------------------------
extern "C" void kernel_launch(void* const* d_in, const int* in_sizes, int n_in,
                              void* d_out, int out_size, void* d_ws, size_t ws_size,
                              hipStream_t stream)
{
    const float* fmaps = (const float*)d_in[0];
    const int*   sel   = (const int*)  d_in[1];
    const float* mean  = (const float*)d_in[2];
    const float* cov   = (const float*)d_in[3];
    const float* minp  = (const float*)d_in[4];
    const float* maxp  = (const float*)d_in[5];
    float* out = (float*)d_out;

    half4* xbuf = (half4*)d_ws;                                   // CC*NPIX4*NN half4 = 5.0 MB
    float* smap = (float*)((char*)d_ws + (size_t)CC*NPIX4*NN*8);  // NN*HW f32 = 0.1 MB (atomic acc)

    {
        const int total = CC * NPIX4;
        prep_x_kernel<<<(total + 255) / 256, 256, 0, stream>>>(fmaps, sel, mean, xbuf, smap);
    }
    qform_kernel<<<NG * NT4, 512, 0, stream>>>(xbuf, cov, smap);
    {
        const int total = NN * OH * OW;
        upsample_kernel<<<(total + 255) / 256, 256, 0, stream>>>(smap, minp, maxp, out);
    }
}